// Round 1
// baseline (270.612 us; speedup 1.0000x reference)
//
#include <hip/hip_runtime.h>
#include <stdint.h>

typedef _Float16 f16;
typedef _Float16 f16x8 __attribute__((ext_vector_type(8)));
typedef float floatx4 __attribute__((ext_vector_type(4)));
typedef unsigned short u16;

#define PDIM 16

__device__ __forceinline__ floatx4 mfma_16x16x32(f16x8 a, f16x8 b, floatx4 c) {
  return __builtin_amdgcn_mfma_f32_16x16x32_f16(a, b, c, 0, 0, 0);
}

// async 16B/lane global->LDS; LDS dst = wave-uniform base + lane*16.
__device__ __forceinline__ void stage16(const f16* g, f16* lds_base) {
  __builtin_amdgcn_global_load_lds(
      (const __attribute__((address_space(1))) void*)g,
      (__attribute__((address_space(3))) void*)lds_base, 16, 0, 0);
}

// raw barrier + fine-grained vmcnt (hipBLASLt-style pipeline control).
#define WAITVM4() asm volatile("s_waitcnt vmcnt(4)" ::: "memory")
#define WAITVM0() asm volatile("s_waitcnt vmcnt(0)" ::: "memory")
#define BAR()     asm volatile("s_barrier" ::: "memory")

// ---- fused prep: [0,2048) transpose W0/W1; [2048,2048+nConvBlk) emb conv;
// then biases+W2 pack (kept fp32 for accuracy). fp32 -> fp16 for big tensors. ----
__global__ __launch_bounds__(256) void kprep(const float* __restrict__ emb,
                                             const float* __restrict__ W0,
                                             const float* __restrict__ W1,
                                             const float* __restrict__ b0,
                                             const float* __restrict__ b1,
                                             const float* __restrict__ W2,
                                             const float* __restrict__ b2,
                                             f16* __restrict__ embB,
                                             f16* __restrict__ W0T,
                                             f16* __restrict__ W1T,
                                             float* __restrict__ smallF,
                                             int n8, int nConvBlk) {
  __shared__ u16 tile[64][72];
  const int b = blockIdx.x;
  const int t = threadIdx.x;
  if (b < 2048) {
    const int m  = b >> 10;
    const int p  = (b >> 6) & 15;
    const int tr = (b >> 3) & 7;
    const int tc = b & 7;
    const float* src = (m ? W1 : W0) + ((size_t)p << 18);
    f16*         dst = (m ? W1T : W0T) + ((size_t)p << 18);
#pragma unroll
    for (int i = 0; i < 2; ++i) {
      int c = t + i * 256;
      int r = c >> 3, s = c & 7;
      const float4* s32 =
          (const float4*)(src + (size_t)(tr * 64 + r) * 512 + tc * 64 + s * 8);
      float4 a = s32[0], bb = s32[1];
      union { f16 h[8]; uint4 v; } o;
      o.h[0] = (f16)a.x;  o.h[1] = (f16)a.y;  o.h[2] = (f16)a.z;  o.h[3] = (f16)a.w;
      o.h[4] = (f16)bb.x; o.h[5] = (f16)bb.y; o.h[6] = (f16)bb.z; o.h[7] = (f16)bb.w;
      *(uint4*)&tile[r][s * 8] = o.v;
    }
    __syncthreads();
#pragma unroll
    for (int i = 0; i < 2; ++i) {
      int c = t + i * 256;
      int r = c >> 3, s = c & 7;
      union { u16 u[8]; uint4 v; } tmp;
#pragma unroll
      for (int j = 0; j < 8; ++j) tmp.u[j] = tile[s * 8 + j][r];
      *(uint4*)(dst + (size_t)(tc * 64 + r) * 512 + tr * 64 + s * 8) = tmp.v;
    }
  } else if (b < 2048 + nConvBlk) {
    const int i = (b - 2048) * 256 + t;
    if (i < n8) {
      const float4* s = (const float4*)emb;
      float4 a = s[i * 2], bb = s[i * 2 + 1];
      union { f16 h[8]; uint4 v; } o;
      o.h[0] = (f16)a.x;  o.h[1] = (f16)a.y;  o.h[2] = (f16)a.z;  o.h[3] = (f16)a.w;
      o.h[4] = (f16)bb.x; o.h[5] = (f16)bb.y; o.h[6] = (f16)bb.z; o.h[7] = (f16)bb.w;
      *(uint4*)(embB + (size_t)i * 8) = o.v;
    }
  } else {
    const int j = (b - 2048 - nConvBlk) * 256 + t;
    if (j < 24592) {
      const float* src;
      int off;
      if (j < 8192)       { src = b0; off = j; }
      else if (j < 16384) { src = b1; off = j - 8192; }
      else if (j < 24576) { src = W2; off = j - 16384; }
      else                { src = b2; off = j - 24576; }
      smallF[j] = src[off];
    }
  }
}

// ---- layer 0: h0 = relu(emb . W0T^T + b0), fp16 out.
// 128x128 tile, BK=32, 16x16x32 MFMA 4x4 acc; TRIPLE-buffered distance-2
// async staging with raw s_barrier + s_waitcnt vmcnt(4) (never full drain).
__global__ __launch_bounds__(256) void kgemm1(const f16* __restrict__ emb,
                                              const f16* __restrict__ W0T,
                                              const float* __restrict__ small,
                                              f16* __restrict__ h0,
                                              int Nc) {
  __shared__ f16 smem[24576];  // A: 3x4096 @0 | B: 3x4096 @12288; epi C 64x136
  const int b  = blockIdx.x;
  const int p  = b & 15;
  const int ht = (b >> 4) & 3;
  const int nt = b >> 6;
  const int n0 = nt * 128;
  const int hc0 = ht * 128;
  const int tid = threadIdx.x;
  const int w = tid >> 6;
  const int lane = tid & 63;
  const int q = lane >> 4;
  const int mm = lane & 15;
  const int wr = (w >> 1) * 64;
  const int wc = (w & 1) * 64;
  const int srow = lane >> 2;
  const int kch  = (lane & 3) * 8;

  const f16* Arow = emb + (size_t)n0 * 512;
  const f16* Brow = W0T + ((size_t)p << 18) + (size_t)hc0 * 512;

  floatx4 acc[4][4];
#pragma unroll
  for (int i = 0; i < 4; ++i)
#pragma unroll
    for (int j = 0; j < 4; ++j) acc[i][j] = floatx4{0.f, 0.f, 0.f, 0.f};

  const int r0 = w * 16 + srow;
  // prologue: tile 0 -> buf0, tile 1 -> buf1 (4 DMAs per group, in order)
#pragma unroll
  for (int tpre = 0; tpre < 2; ++tpre) {
    const int kn = tpre * 32;
    f16* Ab = smem + tpre * 4096;
    f16* Bb = smem + 12288 + tpre * 4096;
    stage16(Arow + (size_t)r0 * 512 + kn + kch, Ab + (w * 16) * 32);
    stage16(Arow + (size_t)(64 + r0) * 512 + kn + kch, Ab + (64 + w * 16) * 32);
    stage16(Brow + (size_t)r0 * 512 + kn + kch, Bb + (w * 16) * 32);
    stage16(Brow + (size_t)(64 + r0) * 512 + kn + kch, Bb + (64 + w * 16) * 32);
  }

#pragma unroll
  for (int it = 0; it < 16; ++it) {
    if (it < 15) { WAITVM4(); } else { WAITVM0(); }  // own tile-it landed
    BAR();  // all waves: tile-it landed; buf[(it+2)%3] no longer being read
    if (it + 2 < 16) {
      const int nb = (it + 2) % 3;
      const int kn = (it + 2) * 32;
      f16* Ab = smem + nb * 4096;
      f16* Bb = smem + 12288 + nb * 4096;
      stage16(Arow + (size_t)r0 * 512 + kn + kch, Ab + (w * 16) * 32);
      stage16(Arow + (size_t)(64 + r0) * 512 + kn + kch, Ab + (64 + w * 16) * 32);
      stage16(Brow + (size_t)r0 * 512 + kn + kch, Bb + (w * 16) * 32);
      stage16(Brow + (size_t)(64 + r0) * 512 + kn + kch, Bb + (64 + w * 16) * 32);
    }
    const int cb = it % 3;
    const f16* A = smem + cb * 4096;
    const f16* B = smem + 12288 + cb * 4096;
    f16x8 af[4], bv[4];
#pragma unroll
    for (int rt = 0; rt < 4; ++rt)
      af[rt] = *(const f16x8*)&A[(wr + rt * 16 + mm) * 32 + q * 8];
#pragma unroll
    for (int ct = 0; ct < 4; ++ct)
      bv[ct] = *(const f16x8*)&B[(wc + ct * 16 + mm) * 32 + q * 8];
#pragma unroll
    for (int rt = 0; rt < 4; ++rt)
#pragma unroll
      for (int ct = 0; ct < 4; ++ct)
        acc[rt][ct] = mfma_16x16x32(af[rt], bv[ct], acc[rt][ct]);
  }

  // coalesced epilogue via LDS (stride 136), two 64-row passes
  __syncthreads();
  f16* Cst = smem;
#pragma unroll
  for (int pass = 0; pass < 2; ++pass) {
    if ((w >> 1) == pass) {
#pragma unroll
      for (int ct = 0; ct < 4; ++ct) {
        const float bvv = small[p * 512 + hc0 + wc + ct * 16 + mm];
#pragma unroll
        for (int rt = 0; rt < 4; ++rt)
#pragma unroll
          for (int r = 0; r < 4; ++r) {
            float v = acc[rt][ct][r] + bvv;
            v = v > 0.f ? v : 0.f;
            Cst[(rt * 16 + q * 4 + r) * 136 + wc + ct * 16 + mm] = (f16)v;
          }
      }
    }
    __syncthreads();
#pragma unroll
    for (int i = 0; i < 4; ++i) {
      const int row = (tid >> 4) + i * 16;
      const int chunk = tid & 15;
      uint4 v = *(const uint4*)&Cst[row * 136 + chunk * 8];
      *(uint4*)&h0[((size_t)p * Nc + n0 + pass * 64 + row) * 512 + hc0 +
                   chunk * 8] = v;
    }
    if (pass == 0) __syncthreads();
  }
}

// ---- layer 1 GEMM + fused partial layer-2 dot; same pipelined core ----
__global__ __launch_bounds__(256) void kgemm2(const f16* __restrict__ h0,
                                              const f16* __restrict__ W1T,
                                              const float* __restrict__ small,
                                              float* __restrict__ pacc,
                                              int Nc) {
  __shared__ f16 smem[24576];
  __shared__ float oacc[128];
  const int b  = blockIdx.x;
  const int p  = b & 15;
  const int ht = (b >> 4) & 3;
  const int nt = b >> 6;
  const int n0 = nt * 128;
  const int hc0 = ht * 128;
  const int tid = threadIdx.x;
  const int w = tid >> 6;
  const int lane = tid & 63;
  const int q = lane >> 4;
  const int mm = lane & 15;
  const int wr = (w >> 1) * 64;
  const int wc = (w & 1) * 64;
  const int srow = lane >> 2;
  const int kch = (lane & 3) * 8;
  if (tid < 128) oacc[tid] = 0.f;

  const f16* Arow = h0 + ((size_t)p * Nc + n0) * 512;
  const f16* Brow = W1T + ((size_t)p << 18) + (size_t)hc0 * 512;

  floatx4 acc[4][4];
#pragma unroll
  for (int i = 0; i < 4; ++i)
#pragma unroll
    for (int j = 0; j < 4; ++j) acc[i][j] = floatx4{0.f, 0.f, 0.f, 0.f};

  const int r0 = w * 16 + srow;
#pragma unroll
  for (int tpre = 0; tpre < 2; ++tpre) {
    const int kn = tpre * 32;
    f16* Ab = smem + tpre * 4096;
    f16* Bb = smem + 12288 + tpre * 4096;
    stage16(Arow + (size_t)r0 * 512 + kn + kch, Ab + (w * 16) * 32);
    stage16(Arow + (size_t)(64 + r0) * 512 + kn + kch, Ab + (64 + w * 16) * 32);
    stage16(Brow + (size_t)r0 * 512 + kn + kch, Bb + (w * 16) * 32);
    stage16(Brow + (size_t)(64 + r0) * 512 + kn + kch, Bb + (64 + w * 16) * 32);
  }

#pragma unroll
  for (int it = 0; it < 16; ++it) {
    if (it < 15) { WAITVM4(); } else { WAITVM0(); }
    BAR();
    if (it + 2 < 16) {
      const int nb = (it + 2) % 3;
      const int kn = (it + 2) * 32;
      f16* Ab = smem + nb * 4096;
      f16* Bb = smem + 12288 + nb * 4096;
      stage16(Arow + (size_t)r0 * 512 + kn + kch, Ab + (w * 16) * 32);
      stage16(Arow + (size_t)(64 + r0) * 512 + kn + kch, Ab + (64 + w * 16) * 32);
      stage16(Brow + (size_t)r0 * 512 + kn + kch, Bb + (w * 16) * 32);
      stage16(Brow + (size_t)(64 + r0) * 512 + kn + kch, Bb + (64 + w * 16) * 32);
    }
    const int cb = it % 3;
    const f16* A = smem + cb * 4096;
    const f16* B = smem + 12288 + cb * 4096;
    f16x8 af[4], bv[4];
#pragma unroll
    for (int rt = 0; rt < 4; ++rt)
      af[rt] = *(const f16x8*)&A[(wr + rt * 16 + mm) * 32 + q * 8];
#pragma unroll
    for (int ct = 0; ct < 4; ++ct)
      bv[ct] = *(const f16x8*)&B[(wc + ct * 16 + mm) * 32 + q * 8];
#pragma unroll
    for (int rt = 0; rt < 4; ++rt)
#pragma unroll
      for (int ct = 0; ct < 4; ++ct)
        acc[rt][ct] = mfma_16x16x32(af[rt], bv[ct], acc[rt][ct]);
  }

  // epilogue: h1 = relu(acc + b1); pd[row] += h1 * W2[col]
  float pd[4][4];
#pragma unroll
  for (int i = 0; i < 4; ++i)
#pragma unroll
    for (int r = 0; r < 4; ++r) pd[i][r] = 0.f;
#pragma unroll
  for (int ct = 0; ct < 4; ++ct) {
    const int col = hc0 + wc + ct * 16 + mm;
    const float b1v = small[8192 + p * 512 + col];
    const float w2v = small[16384 + p * 512 + col];
#pragma unroll
    for (int rt = 0; rt < 4; ++rt)
#pragma unroll
      for (int r = 0; r < 4; ++r) {
        float v = acc[rt][ct][r] + b1v;
        v = v > 0.f ? v : 0.f;
        pd[rt][r] += v * w2v;
      }
  }
#pragma unroll
  for (int rt = 0; rt < 4; ++rt)
#pragma unroll
    for (int r = 0; r < 4; ++r) {
      float v = pd[rt][r];
      v += __shfl_xor(v, 1, 16);
      v += __shfl_xor(v, 2, 16);
      v += __shfl_xor(v, 4, 16);
      v += __shfl_xor(v, 8, 16);
      if (mm == 0) atomicAdd(&oacc[wr + rt * 16 + q * 4 + r], v);
    }
  __syncthreads();
  if (tid < 128)
    pacc[(size_t)(p * 4 + ht) * Nc + n0 + tid] = oacc[tid];
}

// ---- finish: sum 4 ht partials + b2, sigmoid, fp32 out ----
__global__ __launch_bounds__(256) void kfin(const float* __restrict__ pacc,
                                            const float* __restrict__ small,
                                            float* __restrict__ out, int Nc) {
  const int idx = blockIdx.x * 256 + threadIdx.x;
  if (idx >= Nc * 16) return;
  const int n = idx >> 4;
  const int p = idx & 15;
  float v = small[24576 + p];
#pragma unroll
  for (int ht = 0; ht < 4; ++ht) v += pacc[(size_t)(p * 4 + ht) * Nc + n];
  out[(size_t)n * 16 + p] = 1.f / (1.f + expf(-v));
}

// ---- fallback (tiny ws / odd N): slow but correct, fp32 in/out ----
__global__ __launch_bounds__(64) void knaive(const float* __restrict__ emb,
                                             const float* __restrict__ W0,
                                             const float* __restrict__ b0,
                                             const float* __restrict__ W1,
                                             const float* __restrict__ b1,
                                             const float* __restrict__ W2,
                                             const float* __restrict__ b2,
                                             float* __restrict__ out) {
  const int n = blockIdx.x >> 4;
  const int p = blockIdx.x & 15;
  __shared__ float h0s[512];
  __shared__ float h1s[512];
  const size_t wb = (size_t)p << 18;
  const int t = threadIdx.x;
  for (int h = t; h < 512; h += 64) {
    float a = 0.f;
    for (int e = 0; e < 512; ++e)
      a += emb[(size_t)n * 512 + e] * W0[wb + (size_t)e * 512 + h];
    a += b0[p * 512 + h];
    h0s[h] = a > 0.f ? a : 0.f;
  }
  __syncthreads();
  for (int k = t; k < 512; k += 64) {
    float a = 0.f;
    for (int hh = 0; hh < 512; ++hh)
      a += h0s[hh] * W1[wb + (size_t)hh * 512 + k];
    a += b1[p * 512 + k];
    h1s[k] = a > 0.f ? a : 0.f;
  }
  __syncthreads();
  float s = 0.f;
  for (int k = t; k < 512; k += 64) s += h1s[k] * W2[p * 512 + k];
  for (int off = 32; off; off >>= 1) s += __shfl_down(s, off, 64);
  if (t == 0)
    out[(size_t)n * 16 + p] = 1.f / (1.f + expf(-(s + b2[p])));
}

extern "C" void kernel_launch(void* const* d_in, const int* in_sizes, int n_in,
                              void* d_out, int out_size, void* d_ws, size_t ws_size,
                              hipStream_t stream) {
  (void)n_in; (void)out_size;
  const float* emb = (const float*)d_in[0];
  const float* W0  = (const float*)d_in[1];
  const float* b0  = (const float*)d_in[2];
  const float* W1  = (const float*)d_in[3];
  const float* b1  = (const float*)d_in[4];
  const float* W2  = (const float*)d_in[5];
  const float* b2  = (const float*)d_in[6];
  float* out = (float*)d_out;

  const int N = in_sizes[0] / 512;

  char* ws = (char*)d_ws;
  f16*   W0T    = (f16*)ws;                                  // 8 MB
  f16*   W1T    = (f16*)(ws + (8ll << 20));                  // 8 MB
  float* smallF = (float*)(ws + (16ll << 20));               // 128 KB (96.1 used)
  float* pacc   = (float*)(ws + (16ll << 20) + 131072);      // 256*N B
  f16*   embB   = (f16*)(ws + (16ll << 20) + 131072 + (size_t)N * 256);
  f16*   h0     = (f16*)(ws + (16ll << 20) + 131072 + (size_t)N * 256 +
                         (size_t)N * 1024);
  const long long fixed = (16ll << 20) + 131072 + (long long)N * 256 +
                          (long long)N * 1024;
  long long avail = (long long)ws_size - fixed;
  long long rows = avail > 0 ? avail / (16 * 512 * 2) : 0;
  int Nc = (int)((rows / 128) * 128);
  if (Nc > N) Nc = N;

  if (Nc < 128 || (N % 128) != 0) {
    knaive<<<dim3(N * PDIM), dim3(64), 0, stream>>>(emb, W0, b0, W1, b1, W2,
                                                    b2, out);
    return;
  }

  const int n8 = N * 512 / 8;
  const int nConvBlk = (n8 + 255) / 256;
  kprep<<<dim3(2048 + nConvBlk + 97), dim3(256), 0, stream>>>(
      emb, W0, W1, b0, b1, W2, b2, embB, W0T, W1T, smallF, n8, nConvBlk);

  for (int noff = 0; noff < N; noff += Nc) {
    const int cur = (N - noff < Nc) ? (N - noff) : Nc;
    kgemm1<<<dim3(64 * (cur / 128)), dim3(256), 0, stream>>>(
        embB + (size_t)noff * 512, W0T, smallF, h0, cur);
    kgemm2<<<dim3(64 * (cur / 128)), dim3(256), 0, stream>>>(
        h0, W1T, smallF, pacc, cur);
    kfin<<<dim3((cur * 16 + 255) / 256), dim3(256), 0, stream>>>(
        pacc, smallF, out + (size_t)noff * 16, cur);
  }
}

// Round 3
// 266.529 us; speedup vs baseline: 1.0153x; 1.0153x over previous
//
#include <hip/hip_runtime.h>
#include <stdint.h>

typedef _Float16 f16;
typedef _Float16 f16x8 __attribute__((ext_vector_type(8)));
typedef float floatx4 __attribute__((ext_vector_type(4)));
typedef unsigned short u16;

#define PDIM 16

__device__ __forceinline__ floatx4 mfma_16x16x32(f16x8 a, f16x8 b, floatx4 c) {
  return __builtin_amdgcn_mfma_f32_16x16x32_f16(a, b, c, 0, 0, 0);
}

// async 16B/lane global->LDS; LDS dst = wave-uniform base + lane*16.
__device__ __forceinline__ void stage16(const f16* g, f16* lds_base) {
  __builtin_amdgcn_global_load_lds(
      (const __attribute__((address_space(1))) void*)g,
      (__attribute__((address_space(3))) void*)lds_base, 16, 0, 0);
}

// raw barrier + fine-grained vmcnt (hipBLASLt-style pipeline control).
#define WAITVM4() asm volatile("s_waitcnt vmcnt(4)" ::: "memory")
#define WAITVM0() asm volatile("s_waitcnt vmcnt(0)" ::: "memory")
#define BAR()     asm volatile("s_barrier" ::: "memory")
// Fence: pin register-only MFMAs (+their lgkm waits) inside the iteration so
// no ds_read of buf[(it-1)%3] is still pending when the next iteration's DMA
// overwrites it (rule #18: "memory" clobber does not order MFMA).
#define SCHEDFENCE() __builtin_amdgcn_sched_barrier(0)

// LDS granule swizzle (T2 adapted for global_load_lds, rule #21):
//   LDS write stays linear (position = lane). Global source pre-swizzled:
//   lane l fetches chunk c = (l&3) ^ ((l>>3)&3) of row l>>2.
//   Read side: granule (row, q) lives at position row*4 + (q ^ ((row>>1)&3)).
//   Bit-identical arithmetic vs unswizzled.

// ---- fused prep: [0,2048) transpose W0/W1; [2048,2048+nConvBlk) emb conv;
// then biases+W2 pack (kept fp32 for accuracy). fp32 -> fp16 for big tensors. ----
__global__ __launch_bounds__(256) void kprep(const float* __restrict__ emb,
                                             const float* __restrict__ W0,
                                             const float* __restrict__ W1,
                                             const float* __restrict__ b0,
                                             const float* __restrict__ b1,
                                             const float* __restrict__ W2,
                                             const float* __restrict__ b2,
                                             f16* __restrict__ embB,
                                             f16* __restrict__ W0T,
                                             f16* __restrict__ W1T,
                                             float* __restrict__ smallF,
                                             int n8, int nConvBlk) {
  __shared__ u16 tile[64][72];
  const int b = blockIdx.x;
  const int t = threadIdx.x;
  if (b < 2048) {
    const int m  = b >> 10;
    const int p  = (b >> 6) & 15;
    const int tr = (b >> 3) & 7;
    const int tc = b & 7;
    const float* src = (m ? W1 : W0) + ((size_t)p << 18);
    f16*         dst = (m ? W1T : W0T) + ((size_t)p << 18);
#pragma unroll
    for (int i = 0; i < 2; ++i) {
      int c = t + i * 256;
      int r = c >> 3, s = c & 7;
      const float4* s32 =
          (const float4*)(src + (size_t)(tr * 64 + r) * 512 + tc * 64 + s * 8);
      float4 a = s32[0], bb = s32[1];
      union { f16 h[8]; uint4 v; } o;
      o.h[0] = (f16)a.x;  o.h[1] = (f16)a.y;  o.h[2] = (f16)a.z;  o.h[3] = (f16)a.w;
      o.h[4] = (f16)bb.x; o.h[5] = (f16)bb.y; o.h[6] = (f16)bb.z; o.h[7] = (f16)bb.w;
      *(uint4*)&tile[r][s * 8] = o.v;
    }
    __syncthreads();
#pragma unroll
    for (int i = 0; i < 2; ++i) {
      int c = t + i * 256;
      int r = c >> 3, s = c & 7;
      union { u16 u[8]; uint4 v; } tmp;
#pragma unroll
      for (int j = 0; j < 8; ++j) tmp.u[j] = tile[s * 8 + j][r];
      *(uint4*)(dst + (size_t)(tc * 64 + r) * 512 + tr * 64 + s * 8) = tmp.v;
    }
  } else if (b < 2048 + nConvBlk) {
    const int i = (b - 2048) * 256 + t;
    if (i < n8) {
      const float4* s = (const float4*)emb;
      float4 a = s[i * 2], bb = s[i * 2 + 1];
      union { f16 h[8]; uint4 v; } o;
      o.h[0] = (f16)a.x;  o.h[1] = (f16)a.y;  o.h[2] = (f16)a.z;  o.h[3] = (f16)a.w;
      o.h[4] = (f16)bb.x; o.h[5] = (f16)bb.y; o.h[6] = (f16)bb.z; o.h[7] = (f16)bb.w;
      *(uint4*)(embB + (size_t)i * 8) = o.v;
    }
  } else {
    const int j = (b - 2048 - nConvBlk) * 256 + t;
    if (j < 24592) {
      const float* src;
      int off;
      if (j < 8192)       { src = b0; off = j; }
      else if (j < 16384) { src = b1; off = j - 8192; }
      else if (j < 24576) { src = W2; off = j - 16384; }
      else                { src = b2; off = j - 24576; }
      smallF[j] = src[off];
    }
  }
}

// ---- layer 0: h0 = relu(emb . W0T^T + b0), fp16 out.
// 128x128 tile, BK=32, 16x16x32 MFMA 4x4 acc; TRIPLE-buffered distance-2
// async staging with raw s_barrier + s_waitcnt vmcnt(4) (never full drain).
// LDS granule-swizzled; sched_barrier(0) fence per iter (race fix, rule #18).
__global__ __launch_bounds__(256) void kgemm1(const f16* __restrict__ emb,
                                              const f16* __restrict__ W0T,
                                              const float* __restrict__ small,
                                              f16* __restrict__ h0,
                                              int Nc) {
  __shared__ f16 smem[24576];  // A: 3x4096 @0 | B: 3x4096 @12288; epi C 64x136
  const int b  = blockIdx.x;
  const int p  = b & 15;
  const int ht = (b >> 4) & 3;
  const int nt = b >> 6;
  const int n0 = nt * 128;
  const int hc0 = ht * 128;
  const int tid = threadIdx.x;
  const int w = tid >> 6;
  const int lane = tid & 63;
  const int q = lane >> 4;
  const int mm = lane & 15;
  const int wr = (w >> 1) * 64;
  const int wc = (w & 1) * 64;
  const int srow = lane >> 2;
  // pre-swizzled global chunk so linear LDS write lands granule at swizzled pos
  const int kch  = (((lane & 3) ^ ((lane >> 3) & 3)) * 8);
  // swizzled read-side granule offset for this thread's (q, mm)
  const int qs   = (q ^ ((mm >> 1) & 3)) * 8;

  const f16* Arow = emb + (size_t)n0 * 512;
  const f16* Brow = W0T + ((size_t)p << 18) + (size_t)hc0 * 512;

  floatx4 acc[4][4];
#pragma unroll
  for (int i = 0; i < 4; ++i)
#pragma unroll
    for (int j = 0; j < 4; ++j) acc[i][j] = floatx4{0.f, 0.f, 0.f, 0.f};

  const int r0 = w * 16 + srow;
  // prologue: tile 0 -> buf0, tile 1 -> buf1 (4 DMAs per group, in order)
#pragma unroll
  for (int tpre = 0; tpre < 2; ++tpre) {
    const int kn = tpre * 32;
    f16* Ab = smem + tpre * 4096;
    f16* Bb = smem + 12288 + tpre * 4096;
    stage16(Arow + (size_t)r0 * 512 + kn + kch, Ab + (w * 16) * 32);
    stage16(Arow + (size_t)(64 + r0) * 512 + kn + kch, Ab + (64 + w * 16) * 32);
    stage16(Brow + (size_t)r0 * 512 + kn + kch, Bb + (w * 16) * 32);
    stage16(Brow + (size_t)(64 + r0) * 512 + kn + kch, Bb + (64 + w * 16) * 32);
  }

#pragma unroll
  for (int it = 0; it < 16; ++it) {
    if (it < 15) { WAITVM4(); } else { WAITVM0(); }  // own tile-it landed
    BAR();  // all waves: tile-it landed; buf[(it+2)%3] no longer being read
    if (it + 2 < 16) {
      const int nb = (it + 2) % 3;
      const int kn = (it + 2) * 32;
      f16* Ab = smem + nb * 4096;
      f16* Bb = smem + 12288 + nb * 4096;
      stage16(Arow + (size_t)r0 * 512 + kn + kch, Ab + (w * 16) * 32);
      stage16(Arow + (size_t)(64 + r0) * 512 + kn + kch, Ab + (64 + w * 16) * 32);
      stage16(Brow + (size_t)r0 * 512 + kn + kch, Bb + (w * 16) * 32);
      stage16(Brow + (size_t)(64 + r0) * 512 + kn + kch, Bb + (64 + w * 16) * 32);
    }
    const int cb = it % 3;
    const f16* A = smem + cb * 4096;
    const f16* B = smem + 12288 + cb * 4096;
    f16x8 af[4], bv[4];
#pragma unroll
    for (int rt = 0; rt < 4; ++rt)
      af[rt] = *(const f16x8*)&A[(wr + rt * 16 + mm) * 32 + qs];
#pragma unroll
    for (int ct = 0; ct < 4; ++ct)
      bv[ct] = *(const f16x8*)&B[(wc + ct * 16 + mm) * 32 + qs];
#pragma unroll
    for (int rt = 0; rt < 4; ++rt)
#pragma unroll
      for (int ct = 0; ct < 4; ++ct)
        acc[rt][ct] = mfma_16x16x32(af[rt], bv[ct], acc[rt][ct]);
    SCHEDFENCE();  // pin MFMAs + lgkm waits before next iteration's barrier
  }
  SCHEDFENCE();

  // coalesced epilogue via LDS (stride 136), two 64-row passes
  __syncthreads();
  f16* Cst = smem;
#pragma unroll
  for (int pass = 0; pass < 2; ++pass) {
    if ((w >> 1) == pass) {
#pragma unroll
      for (int ct = 0; ct < 4; ++ct) {
        const float bvv = small[p * 512 + hc0 + wc + ct * 16 + mm];
#pragma unroll
        for (int rt = 0; rt < 4; ++rt)
#pragma unroll
          for (int r = 0; r < 4; ++r) {
            float v = acc[rt][ct][r] + bvv;
            v = v > 0.f ? v : 0.f;
            Cst[(rt * 16 + q * 4 + r) * 136 + wc + ct * 16 + mm] = (f16)v;
          }
      }
    }
    __syncthreads();
#pragma unroll
    for (int i = 0; i < 4; ++i) {
      const int row = (tid >> 4) + i * 16;
      const int chunk = tid & 15;
      uint4 v = *(const uint4*)&Cst[row * 136 + chunk * 8];
      *(uint4*)&h0[((size_t)p * Nc + n0 + pass * 64 + row) * 512 + hc0 +
                   chunk * 8] = v;
    }
    if (pass == 0) __syncthreads();
  }
}

// ---- layer 1 GEMM + fused partial layer-2 dot; same pipelined core ----
__global__ __launch_bounds__(256) void kgemm2(const f16* __restrict__ h0,
                                              const f16* __restrict__ W1T,
                                              const float* __restrict__ small,
                                              float* __restrict__ pacc,
                                              int Nc) {
  __shared__ f16 smem[24576];
  __shared__ float oacc[128];
  const int b  = blockIdx.x;
  const int p  = b & 15;
  const int ht = (b >> 4) & 3;
  const int nt = b >> 6;
  const int n0 = nt * 128;
  const int hc0 = ht * 128;
  const int tid = threadIdx.x;
  const int w = tid >> 6;
  const int lane = tid & 63;
  const int q = lane >> 4;
  const int mm = lane & 15;
  const int wr = (w >> 1) * 64;
  const int wc = (w & 1) * 64;
  const int srow = lane >> 2;
  const int kch = (((lane & 3) ^ ((lane >> 3) & 3)) * 8);
  const int qs  = (q ^ ((mm >> 1) & 3)) * 8;
  if (tid < 128) oacc[tid] = 0.f;

  const f16* Arow = h0 + ((size_t)p * Nc + n0) * 512;
  const f16* Brow = W1T + ((size_t)p << 18) + (size_t)hc0 * 512;

  floatx4 acc[4][4];
#pragma unroll
  for (int i = 0; i < 4; ++i)
#pragma unroll
    for (int j = 0; j < 4; ++j) acc[i][j] = floatx4{0.f, 0.f, 0.f, 0.f};

  const int r0 = w * 16 + srow;
#pragma unroll
  for (int tpre = 0; tpre < 2; ++tpre) {
    const int kn = tpre * 32;
    f16* Ab = smem + tpre * 4096;
    f16* Bb = smem + 12288 + tpre * 4096;
    stage16(Arow + (size_t)r0 * 512 + kn + kch, Ab + (w * 16) * 32);
    stage16(Arow + (size_t)(64 + r0) * 512 + kn + kch, Ab + (64 + w * 16) * 32);
    stage16(Brow + (size_t)r0 * 512 + kn + kch, Bb + (w * 16) * 32);
    stage16(Brow + (size_t)(64 + r0) * 512 + kn + kch, Bb + (64 + w * 16) * 32);
  }

#pragma unroll
  for (int it = 0; it < 16; ++it) {
    if (it < 15) { WAITVM4(); } else { WAITVM0(); }
    BAR();
    if (it + 2 < 16) {
      const int nb = (it + 2) % 3;
      const int kn = (it + 2) * 32;
      f16* Ab = smem + nb * 4096;
      f16* Bb = smem + 12288 + nb * 4096;
      stage16(Arow + (size_t)r0 * 512 + kn + kch, Ab + (w * 16) * 32);
      stage16(Arow + (size_t)(64 + r0) * 512 + kn + kch, Ab + (64 + w * 16) * 32);
      stage16(Brow + (size_t)r0 * 512 + kn + kch, Bb + (w * 16) * 32);
      stage16(Brow + (size_t)(64 + r0) * 512 + kn + kch, Bb + (64 + w * 16) * 32);
    }
    const int cb = it % 3;
    const f16* A = smem + cb * 4096;
    const f16* B = smem + 12288 + cb * 4096;
    f16x8 af[4], bv[4];
#pragma unroll
    for (int rt = 0; rt < 4; ++rt)
      af[rt] = *(const f16x8*)&A[(wr + rt * 16 + mm) * 32 + qs];
#pragma unroll
    for (int ct = 0; ct < 4; ++ct)
      bv[ct] = *(const f16x8*)&B[(wc + ct * 16 + mm) * 32 + qs];
#pragma unroll
    for (int rt = 0; rt < 4; ++rt)
#pragma unroll
      for (int ct = 0; ct < 4; ++ct)
        acc[rt][ct] = mfma_16x16x32(af[rt], bv[ct], acc[rt][ct]);
    SCHEDFENCE();  // pin MFMAs + lgkm waits before next iteration's barrier
  }
  SCHEDFENCE();

  // epilogue: h1 = relu(acc + b1); pd[row] += h1 * W2[col]
  float pd[4][4];
#pragma unroll
  for (int i = 0; i < 4; ++i)
#pragma unroll
    for (int r = 0; r < 4; ++r) pd[i][r] = 0.f;
#pragma unroll
  for (int ct = 0; ct < 4; ++ct) {
    const int col = hc0 + wc + ct * 16 + mm;
    const float b1v = small[8192 + p * 512 + col];
    const float w2v = small[16384 + p * 512 + col];
#pragma unroll
    for (int rt = 0; rt < 4; ++rt)
#pragma unroll
      for (int r = 0; r < 4; ++r) {
        float v = acc[rt][ct][r] + b1v;
        v = v > 0.f ? v : 0.f;
        pd[rt][r] += v * w2v;
      }
  }
#pragma unroll
  for (int rt = 0; rt < 4; ++rt)
#pragma unroll
    for (int r = 0; r < 4; ++r) {
      float v = pd[rt][r];
      v += __shfl_xor(v, 1, 16);
      v += __shfl_xor(v, 2, 16);
      v += __shfl_xor(v, 4, 16);
      v += __shfl_xor(v, 8, 16);
      if (mm == 0) atomicAdd(&oacc[wr + rt * 16 + q * 4 + r], v);
    }
  __syncthreads();
  if (tid < 128)
    pacc[(size_t)(p * 4 + ht) * Nc + n0 + tid] = oacc[tid];
}

// ---- finish: sum 4 ht partials + b2, sigmoid, fp32 out ----
__global__ __launch_bounds__(256) void kfin(const float* __restrict__ pacc,
                                            const float* __restrict__ small,
                                            float* __restrict__ out, int Nc) {
  const int idx = blockIdx.x * 256 + threadIdx.x;
  if (idx >= Nc * 16) return;
  const int n = idx >> 4;
  const int p = idx & 15;
  float v = small[24576 + p];
#pragma unroll
  for (int ht = 0; ht < 4; ++ht) v += pacc[(size_t)(p * 4 + ht) * Nc + n];
  out[(size_t)n * 16 + p] = 1.f / (1.f + expf(-v));
}

// ---- fallback (tiny ws / odd N): slow but correct, fp32 in/out ----
__global__ __launch_bounds__(64) void knaive(const float* __restrict__ emb,
                                             const float* __restrict__ W0,
                                             const float* __restrict__ b0,
                                             const float* __restrict__ W1,
                                             const float* __restrict__ b1,
                                             const float* __restrict__ W2,
                                             const float* __restrict__ b2,
                                             float* __restrict__ out) {
  const int n = blockIdx.x >> 4;
  const int p = blockIdx.x & 15;
  __shared__ float h0s[512];
  __shared__ float h1s[512];
  const size_t wb = (size_t)p << 18;
  const int t = threadIdx.x;
  for (int h = t; h < 512; h += 64) {
    float a = 0.f;
    for (int e = 0; e < 512; ++e)
      a += emb[(size_t)n * 512 + e] * W0[wb + (size_t)e * 512 + h];
    a += b0[p * 512 + h];
    h0s[h] = a > 0.f ? a : 0.f;
  }
  __syncthreads();
  for (int k = t; k < 512; k += 64) {
    float a = 0.f;
    for (int hh = 0; hh < 512; ++hh)
      a += h0s[hh] * W1[wb + (size_t)hh * 512 + k];
    a += b1[p * 512 + k];
    h1s[k] = a > 0.f ? a : 0.f;
  }
  __syncthreads();
  float s = 0.f;
  for (int k = t; k < 512; k += 64) s += h1s[k] * W2[p * 512 + k];
  for (int off = 32; off; off >>= 1) s += __shfl_down(s, off, 64);
  if (t == 0)
    out[(size_t)n * 16 + p] = 1.f / (1.f + expf(-(s + b2[p])));
}

extern "C" void kernel_launch(void* const* d_in, const int* in_sizes, int n_in,
                              void* d_out, int out_size, void* d_ws, size_t ws_size,
                              hipStream_t stream) {
  (void)n_in; (void)out_size;
  const float* emb = (const float*)d_in[0];
  const float* W0  = (const float*)d_in[1];
  const float* b0  = (const float*)d_in[2];
  const float* W1  = (const float*)d_in[3];
  const float* b1  = (const float*)d_in[4];
  const float* W2  = (const float*)d_in[5];
  const float* b2  = (const float*)d_in[6];
  float* out = (float*)d_out;

  const int N = in_sizes[0] / 512;

  char* ws = (char*)d_ws;
  f16*   W0T    = (f16*)ws;                                  // 8 MB
  f16*   W1T    = (f16*)(ws + (8ll << 20));                  // 8 MB
  float* smallF = (float*)(ws + (16ll << 20));               // 128 KB (96.1 used)
  float* pacc   = (float*)(ws + (16ll << 20) + 131072);      // 256*N B
  f16*   embB   = (f16*)(ws + (16ll << 20) + 131072 + (size_t)N * 256);
  f16*   h0     = (f16*)(ws + (16ll << 20) + 131072 + (size_t)N * 256 +
                         (size_t)N * 1024);
  const long long fixed = (16ll << 20) + 131072 + (long long)N * 256 +
                          (long long)N * 1024;
  long long avail = (long long)ws_size - fixed;
  long long rows = avail > 0 ? avail / (16 * 512 * 2) : 0;
  int Nc = (int)((rows / 128) * 128);
  if (Nc > N) Nc = N;

  if (Nc < 128 || (N % 128) != 0) {
    knaive<<<dim3(N * PDIM), dim3(64), 0, stream>>>(emb, W0, b0, W1, b1, W2,
                                                    b2, out);
    return;
  }

  const int n8 = N * 512 / 8;
  const int nConvBlk = (n8 + 255) / 256;
  kprep<<<dim3(2048 + nConvBlk + 97), dim3(256), 0, stream>>>(
      emb, W0, W1, b0, b1, W2, b2, embB, W0T, W1T, smallF, n8, nConvBlk);

  for (int noff = 0; noff < N; noff += Nc) {
    const int cur = (N - noff < Nc) ? (N - noff) : Nc;
    kgemm1<<<dim3(64 * (cur / 128)), dim3(256), 0, stream>>>(
        embB + (size_t)noff * 512, W0T, smallF, h0, cur);
    kgemm2<<<dim3(64 * (cur / 128)), dim3(256), 0, stream>>>(
        h0, W1T, smallF, pacc, cur);
    kfin<<<dim3((cur * 16 + 255) / 256), dim3(256), 0, stream>>>(
        pacc, smallF, out + (size_t)noff * 16, cur);
  }
}

// Round 4
// 262.740 us; speedup vs baseline: 1.0300x; 1.0144x over previous
//
#include <hip/hip_runtime.h>
#include <stdint.h>

typedef _Float16 f16;
typedef _Float16 f16x8 __attribute__((ext_vector_type(8)));
typedef float floatx4 __attribute__((ext_vector_type(4)));
typedef unsigned short u16;

#define PDIM 16

__device__ __forceinline__ floatx4 mfma_16x16x32(f16x8 a, f16x8 b, floatx4 c) {
  return __builtin_amdgcn_mfma_f32_16x16x32_f16(a, b, c, 0, 0, 0);
}

// async 16B/lane global->LDS; LDS dst = wave-uniform base + lane*16.
__device__ __forceinline__ void stage16(const f16* g, f16* lds_base) {
  __builtin_amdgcn_global_load_lds(
      (const __attribute__((address_space(1))) void*)g,
      (__attribute__((address_space(3))) void*)lds_base, 16, 0, 0);
}

// raw barrier + fine-grained vmcnt (hipBLASLt-style pipeline control).
#define WAITVM4() asm volatile("s_waitcnt vmcnt(4)" ::: "memory")
#define WAITVM0() asm volatile("s_waitcnt vmcnt(0)" ::: "memory")
#define BAR()     asm volatile("s_barrier" ::: "memory")
// Fence: pin register-only MFMAs (+their lgkm waits) inside the iteration so
// no ds_read of buf[(it-1)%3] is still pending when the next iteration's DMA
// overwrites it (rule #18: "memory" clobber does not order MFMA).
#define SCHEDFENCE() __builtin_amdgcn_sched_barrier(0)

// XCD-affinity block swizzle (T1): XCD x (= b&7 under round-robin dispatch)
// owns p in {2x,2x+1}; iterates nt-groups of 8 with ht innermost. Per-XCD L2
// working set: A-tiles ~1-2 MB + B-tiles 1 MB < 4 MB -> weights fetched from
// L3 once per XCD, A-tiles L2-hit across their sharers. Bijective for NT%8==0
// (identity fallback otherwise). Pure index remap; per-block work unchanged.
__device__ __forceinline__ void decode_block(int b, int nwg, int& p, int& ht,
                                             int& nt) {
  const int NT = nwg >> 6;  // number of 128-row n-tiles
  if ((NT & 7) == 0) {
    const int x  = b & 7;        // XCD id under round-robin dispatch
    const int u  = b >> 3;       // sequence within XCD, [0, 8*NT)
    const int cg = u >> 6;       // nt-group index, [0, NT/8)
    const int i  = u & 63;       // 8 ntl x 2 pl x 4 ht
    ht = i & 3;
    const int pl  = (i >> 2) & 1;
    const int ntl = i >> 3;
    p  = x * 2 + pl;
    nt = cg * 8 + ntl;
  } else {
    p  = b & 15;
    ht = (b >> 4) & 3;
    nt = b >> 6;
  }
}

// LDS granule swizzle (T2 adapted for global_load_lds, rule #21):
//   LDS write stays linear (position = lane). Global source pre-swizzled:
//   lane l fetches chunk c = (l&3) ^ ((l>>3)&3) of row l>>2.
//   Read side: granule (row, q) lives at position row*4 + (q ^ ((row>>1)&3)).
//   Bit-identical arithmetic vs unswizzled.

// ---- fused prep: [0,2048) transpose W0/W1; [2048,2048+nConvBlk) emb conv;
// then biases+W2 pack (kept fp32 for accuracy). fp32 -> fp16 for big tensors. ----
__global__ __launch_bounds__(256) void kprep(const float* __restrict__ emb,
                                             const float* __restrict__ W0,
                                             const float* __restrict__ W1,
                                             const float* __restrict__ b0,
                                             const float* __restrict__ b1,
                                             const float* __restrict__ W2,
                                             const float* __restrict__ b2,
                                             f16* __restrict__ embB,
                                             f16* __restrict__ W0T,
                                             f16* __restrict__ W1T,
                                             float* __restrict__ smallF,
                                             int n8, int nConvBlk) {
  __shared__ u16 tile[64][72];
  const int b = blockIdx.x;
  const int t = threadIdx.x;
  if (b < 2048) {
    const int m  = b >> 10;
    const int p  = (b >> 6) & 15;
    const int tr = (b >> 3) & 7;
    const int tc = b & 7;
    const float* src = (m ? W1 : W0) + ((size_t)p << 18);
    f16*         dst = (m ? W1T : W0T) + ((size_t)p << 18);
#pragma unroll
    for (int i = 0; i < 2; ++i) {
      int c = t + i * 256;
      int r = c >> 3, s = c & 7;
      const float4* s32 =
          (const float4*)(src + (size_t)(tr * 64 + r) * 512 + tc * 64 + s * 8);
      float4 a = s32[0], bb = s32[1];
      union { f16 h[8]; uint4 v; } o;
      o.h[0] = (f16)a.x;  o.h[1] = (f16)a.y;  o.h[2] = (f16)a.z;  o.h[3] = (f16)a.w;
      o.h[4] = (f16)bb.x; o.h[5] = (f16)bb.y; o.h[6] = (f16)bb.z; o.h[7] = (f16)bb.w;
      *(uint4*)&tile[r][s * 8] = o.v;
    }
    __syncthreads();
#pragma unroll
    for (int i = 0; i < 2; ++i) {
      int c = t + i * 256;
      int r = c >> 3, s = c & 7;
      union { u16 u[8]; uint4 v; } tmp;
#pragma unroll
      for (int j = 0; j < 8; ++j) tmp.u[j] = tile[s * 8 + j][r];
      *(uint4*)(dst + (size_t)(tc * 64 + r) * 512 + tr * 64 + s * 8) = tmp.v;
    }
  } else if (b < 2048 + nConvBlk) {
    const int i = (b - 2048) * 256 + t;
    if (i < n8) {
      const float4* s = (const float4*)emb;
      float4 a = s[i * 2], bb = s[i * 2 + 1];
      union { f16 h[8]; uint4 v; } o;
      o.h[0] = (f16)a.x;  o.h[1] = (f16)a.y;  o.h[2] = (f16)a.z;  o.h[3] = (f16)a.w;
      o.h[4] = (f16)bb.x; o.h[5] = (f16)bb.y; o.h[6] = (f16)bb.z; o.h[7] = (f16)bb.w;
      *(uint4*)(embB + (size_t)i * 8) = o.v;
    }
  } else {
    const int j = (b - 2048 - nConvBlk) * 256 + t;
    if (j < 24592) {
      const float* src;
      int off;
      if (j < 8192)       { src = b0; off = j; }
      else if (j < 16384) { src = b1; off = j - 8192; }
      else if (j < 24576) { src = W2; off = j - 16384; }
      else                { src = b2; off = j - 24576; }
      smallF[j] = src[off];
    }
  }
}

// ---- layer 0: h0 = relu(emb . W0T^T + b0), fp16 out.
// 128x128 tile, BK=32, 16x16x32 MFMA 4x4 acc; TRIPLE-buffered distance-2
// async staging with raw s_barrier + s_waitcnt vmcnt(4) (never full drain).
// LDS granule-swizzled; sched_barrier(0) fence per iter (race fix, rule #18);
// XCD-affinity block swizzle (T1) for L2-resident staging.
__global__ __launch_bounds__(256) void kgemm1(const f16* __restrict__ emb,
                                              const f16* __restrict__ W0T,
                                              const float* __restrict__ small,
                                              f16* __restrict__ h0,
                                              int Nc) {
  __shared__ f16 smem[24576];  // A: 3x4096 @0 | B: 3x4096 @12288; epi C 64x136
  int p, ht, nt;
  decode_block(blockIdx.x, gridDim.x, p, ht, nt);
  const int n0 = nt * 128;
  const int hc0 = ht * 128;
  const int tid = threadIdx.x;
  const int w = tid >> 6;
  const int lane = tid & 63;
  const int q = lane >> 4;
  const int mm = lane & 15;
  const int wr = (w >> 1) * 64;
  const int wc = (w & 1) * 64;
  const int srow = lane >> 2;
  // pre-swizzled global chunk so linear LDS write lands granule at swizzled pos
  const int kch  = (((lane & 3) ^ ((lane >> 3) & 3)) * 8);
  // swizzled read-side granule offset for this thread's (q, mm)
  const int qs   = (q ^ ((mm >> 1) & 3)) * 8;

  const f16* Arow = emb + (size_t)n0 * 512;
  const f16* Brow = W0T + ((size_t)p << 18) + (size_t)hc0 * 512;

  floatx4 acc[4][4];
#pragma unroll
  for (int i = 0; i < 4; ++i)
#pragma unroll
    for (int j = 0; j < 4; ++j) acc[i][j] = floatx4{0.f, 0.f, 0.f, 0.f};

  const int r0 = w * 16 + srow;
  // prologue: tile 0 -> buf0, tile 1 -> buf1 (4 DMAs per group, in order)
#pragma unroll
  for (int tpre = 0; tpre < 2; ++tpre) {
    const int kn = tpre * 32;
    f16* Ab = smem + tpre * 4096;
    f16* Bb = smem + 12288 + tpre * 4096;
    stage16(Arow + (size_t)r0 * 512 + kn + kch, Ab + (w * 16) * 32);
    stage16(Arow + (size_t)(64 + r0) * 512 + kn + kch, Ab + (64 + w * 16) * 32);
    stage16(Brow + (size_t)r0 * 512 + kn + kch, Bb + (w * 16) * 32);
    stage16(Brow + (size_t)(64 + r0) * 512 + kn + kch, Bb + (64 + w * 16) * 32);
  }

#pragma unroll
  for (int it = 0; it < 16; ++it) {
    if (it < 15) { WAITVM4(); } else { WAITVM0(); }  // own tile-it landed
    BAR();  // all waves: tile-it landed; buf[(it+2)%3] no longer being read
    if (it + 2 < 16) {
      const int nb = (it + 2) % 3;
      const int kn = (it + 2) * 32;
      f16* Ab = smem + nb * 4096;
      f16* Bb = smem + 12288 + nb * 4096;
      stage16(Arow + (size_t)r0 * 512 + kn + kch, Ab + (w * 16) * 32);
      stage16(Arow + (size_t)(64 + r0) * 512 + kn + kch, Ab + (64 + w * 16) * 32);
      stage16(Brow + (size_t)r0 * 512 + kn + kch, Bb + (w * 16) * 32);
      stage16(Brow + (size_t)(64 + r0) * 512 + kn + kch, Bb + (64 + w * 16) * 32);
    }
    const int cb = it % 3;
    const f16* A = smem + cb * 4096;
    const f16* B = smem + 12288 + cb * 4096;
    f16x8 af[4], bv[4];
#pragma unroll
    for (int rt = 0; rt < 4; ++rt)
      af[rt] = *(const f16x8*)&A[(wr + rt * 16 + mm) * 32 + qs];
#pragma unroll
    for (int ct = 0; ct < 4; ++ct)
      bv[ct] = *(const f16x8*)&B[(wc + ct * 16 + mm) * 32 + qs];
#pragma unroll
    for (int rt = 0; rt < 4; ++rt)
#pragma unroll
      for (int ct = 0; ct < 4; ++ct)
        acc[rt][ct] = mfma_16x16x32(af[rt], bv[ct], acc[rt][ct]);
    SCHEDFENCE();  // pin MFMAs + lgkm waits before next iteration's barrier
  }
  SCHEDFENCE();

  // coalesced epilogue via LDS (stride 136), two 64-row passes
  __syncthreads();
  f16* Cst = smem;
#pragma unroll
  for (int pass = 0; pass < 2; ++pass) {
    if ((w >> 1) == pass) {
#pragma unroll
      for (int ct = 0; ct < 4; ++ct) {
        const float bvv = small[p * 512 + hc0 + wc + ct * 16 + mm];
#pragma unroll
        for (int rt = 0; rt < 4; ++rt)
#pragma unroll
          for (int r = 0; r < 4; ++r) {
            float v = acc[rt][ct][r] + bvv;
            v = v > 0.f ? v : 0.f;
            Cst[(rt * 16 + q * 4 + r) * 136 + wc + ct * 16 + mm] = (f16)v;
          }
      }
    }
    __syncthreads();
#pragma unroll
    for (int i = 0; i < 4; ++i) {
      const int row = (tid >> 4) + i * 16;
      const int chunk = tid & 15;
      uint4 v = *(const uint4*)&Cst[row * 136 + chunk * 8];
      *(uint4*)&h0[((size_t)p * Nc + n0 + pass * 64 + row) * 512 + hc0 +
                   chunk * 8] = v;
    }
    if (pass == 0) __syncthreads();
  }
}

// ---- layer 1 GEMM + fused partial layer-2 dot; same pipelined core ----
__global__ __launch_bounds__(256) void kgemm2(const f16* __restrict__ h0,
                                              const f16* __restrict__ W1T,
                                              const float* __restrict__ small,
                                              float* __restrict__ pacc,
                                              int Nc) {
  __shared__ f16 smem[24576];
  __shared__ float oacc[128];
  int p, ht, nt;
  decode_block(blockIdx.x, gridDim.x, p, ht, nt);
  const int n0 = nt * 128;
  const int hc0 = ht * 128;
  const int tid = threadIdx.x;
  const int w = tid >> 6;
  const int lane = tid & 63;
  const int q = lane >> 4;
  const int mm = lane & 15;
  const int wr = (w >> 1) * 64;
  const int wc = (w & 1) * 64;
  const int srow = lane >> 2;
  const int kch = (((lane & 3) ^ ((lane >> 3) & 3)) * 8);
  const int qs  = (q ^ ((mm >> 1) & 3)) * 8;
  if (tid < 128) oacc[tid] = 0.f;

  const f16* Arow = h0 + ((size_t)p * Nc + n0) * 512;
  const f16* Brow = W1T + ((size_t)p << 18) + (size_t)hc0 * 512;

  floatx4 acc[4][4];
#pragma unroll
  for (int i = 0; i < 4; ++i)
#pragma unroll
    for (int j = 0; j < 4; ++j) acc[i][j] = floatx4{0.f, 0.f, 0.f, 0.f};

  const int r0 = w * 16 + srow;
#pragma unroll
  for (int tpre = 0; tpre < 2; ++tpre) {
    const int kn = tpre * 32;
    f16* Ab = smem + tpre * 4096;
    f16* Bb = smem + 12288 + tpre * 4096;
    stage16(Arow + (size_t)r0 * 512 + kn + kch, Ab + (w * 16) * 32);
    stage16(Arow + (size_t)(64 + r0) * 512 + kn + kch, Ab + (64 + w * 16) * 32);
    stage16(Brow + (size_t)r0 * 512 + kn + kch, Bb + (w * 16) * 32);
    stage16(Brow + (size_t)(64 + r0) * 512 + kn + kch, Bb + (64 + w * 16) * 32);
  }

#pragma unroll
  for (int it = 0; it < 16; ++it) {
    if (it < 15) { WAITVM4(); } else { WAITVM0(); }
    BAR();
    if (it + 2 < 16) {
      const int nb = (it + 2) % 3;
      const int kn = (it + 2) * 32;
      f16* Ab = smem + nb * 4096;
      f16* Bb = smem + 12288 + nb * 4096;
      stage16(Arow + (size_t)r0 * 512 + kn + kch, Ab + (w * 16) * 32);
      stage16(Arow + (size_t)(64 + r0) * 512 + kn + kch, Ab + (64 + w * 16) * 32);
      stage16(Brow + (size_t)r0 * 512 + kn + kch, Bb + (w * 16) * 32);
      stage16(Brow + (size_t)(64 + r0) * 512 + kn + kch, Bb + (64 + w * 16) * 32);
    }
    const int cb = it % 3;
    const f16* A = smem + cb * 4096;
    const f16* B = smem + 12288 + cb * 4096;
    f16x8 af[4], bv[4];
#pragma unroll
    for (int rt = 0; rt < 4; ++rt)
      af[rt] = *(const f16x8*)&A[(wr + rt * 16 + mm) * 32 + qs];
#pragma unroll
    for (int ct = 0; ct < 4; ++ct)
      bv[ct] = *(const f16x8*)&B[(wc + ct * 16 + mm) * 32 + qs];
#pragma unroll
    for (int rt = 0; rt < 4; ++rt)
#pragma unroll
      for (int ct = 0; ct < 4; ++ct)
        acc[rt][ct] = mfma_16x16x32(af[rt], bv[ct], acc[rt][ct]);
    SCHEDFENCE();  // pin MFMAs + lgkm waits before next iteration's barrier
  }
  SCHEDFENCE();

  // epilogue: h1 = relu(acc + b1); pd[row] += h1 * W2[col]
  float pd[4][4];
#pragma unroll
  for (int i = 0; i < 4; ++i)
#pragma unroll
    for (int r = 0; r < 4; ++r) pd[i][r] = 0.f;
#pragma unroll
  for (int ct = 0; ct < 4; ++ct) {
    const int col = hc0 + wc + ct * 16 + mm;
    const float b1v = small[8192 + p * 512 + col];
    const float w2v = small[16384 + p * 512 + col];
#pragma unroll
    for (int rt = 0; rt < 4; ++rt)
#pragma unroll
      for (int r = 0; r < 4; ++r) {
        float v = acc[rt][ct][r] + b1v;
        v = v > 0.f ? v : 0.f;
        pd[rt][r] += v * w2v;
      }
  }
#pragma unroll
  for (int rt = 0; rt < 4; ++rt)
#pragma unroll
    for (int r = 0; r < 4; ++r) {
      float v = pd[rt][r];
      v += __shfl_xor(v, 1, 16);
      v += __shfl_xor(v, 2, 16);
      v += __shfl_xor(v, 4, 16);
      v += __shfl_xor(v, 8, 16);
      if (mm == 0) atomicAdd(&oacc[wr + rt * 16 + q * 4 + r], v);
    }
  __syncthreads();
  if (tid < 128)
    pacc[(size_t)(p * 4 + ht) * Nc + n0 + tid] = oacc[tid];
}

// ---- finish: sum 4 ht partials + b2, sigmoid, fp32 out ----
__global__ __launch_bounds__(256) void kfin(const float* __restrict__ pacc,
                                            const float* __restrict__ small,
                                            float* __restrict__ out, int Nc) {
  const int idx = blockIdx.x * 256 + threadIdx.x;
  if (idx >= Nc * 16) return;
  const int n = idx >> 4;
  const int p = idx & 15;
  float v = small[24576 + p];
#pragma unroll
  for (int ht = 0; ht < 4; ++ht) v += pacc[(size_t)(p * 4 + ht) * Nc + n];
  out[(size_t)n * 16 + p] = 1.f / (1.f + expf(-v));
}

// ---- fallback (tiny ws / odd N): slow but correct, fp32 in/out ----
__global__ __launch_bounds__(64) void knaive(const float* __restrict__ emb,
                                             const float* __restrict__ W0,
                                             const float* __restrict__ b0,
                                             const float* __restrict__ W1,
                                             const float* __restrict__ b1,
                                             const float* __restrict__ W2,
                                             const float* __restrict__ b2,
                                             float* __restrict__ out) {
  const int n = blockIdx.x >> 4;
  const int p = blockIdx.x & 15;
  __shared__ float h0s[512];
  __shared__ float h1s[512];
  const size_t wb = (size_t)p << 18;
  const int t = threadIdx.x;
  for (int h = t; h < 512; h += 64) {
    float a = 0.f;
    for (int e = 0; e < 512; ++e)
      a += emb[(size_t)n * 512 + e] * W0[wb + (size_t)e * 512 + h];
    a += b0[p * 512 + h];
    h0s[h] = a > 0.f ? a : 0.f;
  }
  __syncthreads();
  for (int k = t; k < 512; k += 64) {
    float a = 0.f;
    for (int hh = 0; hh < 512; ++hh)
      a += h0s[hh] * W1[wb + (size_t)hh * 512 + k];
    a += b1[p * 512 + k];
    h1s[k] = a > 0.f ? a : 0.f;
  }
  __syncthreads();
  float s = 0.f;
  for (int k = t; k < 512; k += 64) s += h1s[k] * W2[p * 512 + k];
  for (int off = 32; off; off >>= 1) s += __shfl_down(s, off, 64);
  if (t == 0)
    out[(size_t)n * 16 + p] = 1.f / (1.f + expf(-(s + b2[p])));
}

extern "C" void kernel_launch(void* const* d_in, const int* in_sizes, int n_in,
                              void* d_out, int out_size, void* d_ws, size_t ws_size,
                              hipStream_t stream) {
  (void)n_in; (void)out_size;
  const float* emb = (const float*)d_in[0];
  const float* W0  = (const float*)d_in[1];
  const float* b0  = (const float*)d_in[2];
  const float* W1  = (const float*)d_in[3];
  const float* b1  = (const float*)d_in[4];
  const float* W2  = (const float*)d_in[5];
  const float* b2  = (const float*)d_in[6];
  float* out = (float*)d_out;

  const int N = in_sizes[0] / 512;

  char* ws = (char*)d_ws;
  f16*   W0T    = (f16*)ws;                                  // 8 MB
  f16*   W1T    = (f16*)(ws + (8ll << 20));                  // 8 MB
  float* smallF = (float*)(ws + (16ll << 20));               // 128 KB (96.1 used)
  float* pacc   = (float*)(ws + (16ll << 20) + 131072);      // 256*N B
  f16*   embB   = (f16*)(ws + (16ll << 20) + 131072 + (size_t)N * 256);
  f16*   h0     = (f16*)(ws + (16ll << 20) + 131072 + (size_t)N * 256 +
                         (size_t)N * 1024);
  const long long fixed = (16ll << 20) + 131072 + (long long)N * 256 +
                          (long long)N * 1024;
  long long avail = (long long)ws_size - fixed;
  long long rows = avail > 0 ? avail / (16 * 512 * 2) : 0;
  int Nc = (int)((rows / 128) * 128);
  if (Nc > N) Nc = N;

  if (Nc < 128 || (N % 128) != 0) {
    knaive<<<dim3(N * PDIM), dim3(64), 0, stream>>>(emb, W0, b0, W1, b1, W2,
                                                    b2, out);
    return;
  }

  const int n8 = N * 512 / 8;
  const int nConvBlk = (n8 + 255) / 256;
  kprep<<<dim3(2048 + nConvBlk + 97), dim3(256), 0, stream>>>(
      emb, W0, W1, b0, b1, W2, b2, embB, W0T, W1T, smallF, n8, nConvBlk);

  for (int noff = 0; noff < N; noff += Nc) {
    const int cur = (N - noff < Nc) ? (N - noff) : Nc;
    kgemm1<<<dim3(64 * (cur / 128)), dim3(256), 0, stream>>>(
        embB + (size_t)noff * 512, W0T, smallF, h0, cur);
    kgemm2<<<dim3(64 * (cur / 128)), dim3(256), 0, stream>>>(
        h0, W1T, smallF, pacc, cur);
    kfin<<<dim3((cur * 16 + 255) / 256), dim3(256), 0, stream>>>(
        pacc, smallF, out + (size_t)noff * 16, cur);
  }
}